// Round 1
// baseline (900.141 us; speedup 1.0000x reference)
//
#include <hip/hip_runtime.h>
#include <hip/hip_bf16.h>
#include <hip/hip_fp16.h>
#include <stdint.h>

typedef float    f32x4 __attribute__((ext_vector_type(4)));
typedef float    fvec4 __attribute__((ext_vector_type(4)));
typedef _Float16 f16x8 __attribute__((ext_vector_type(8)));

#define D_MODEL 1024
#define D_FF    4096
#define NTOK    8192
#define CAP_ROWS 16896  // 132 * 128

// ---- workspace layout (bytes) ----
#define OFF_W1  0UL           // 4*4096*1024*2 = 33,554,432 (W1^T fp16: [e][n][k])
#define OFF_W2  33554432UL    // 4*1024*4096*2 = 33,554,432 (W2^T fp16: [e][d][f])
#define OFF_XG  67108864UL    // 16896*1024*2 = 34,603,008 (gathered x, fp16)
#define OFF_H   101711872UL   // 16896*4096*2 = 138,412,032 (hidden, fp16)
#define OFF_CNT 240123904UL   // 4 int
#define OFF_CUR 240123920UL   // 4 int
#define OFF_OFS 240123936UL   // 5 int
#define OFF_TOK 240124160UL   // 16896 int
#define OFF_WGT 240191744UL   // 16896 float
#define OFF_E12 240259328UL   // 8192 int
#define OFF_W12 240292096UL   // 16384 float
#define WS_NEED 240357632UL

__device__ __forceinline__ void gload_lds16(const void* g, void* l) {
  __builtin_amdgcn_global_load_lds(
      (const __attribute__((address_space(1))) unsigned int*)g,
      (__attribute__((address_space(3))) unsigned int*)l, 16, 0, 0);
}

// ---------------- router: fp32 logits, top-2, renormalized probs ----------------
__global__ __launch_bounds__(256) void router_k(
    const float* __restrict__ x, const float* __restrict__ Wr,
    const float* __restrict__ br, int* __restrict__ counts,
    int* __restrict__ e12, float* __restrict__ w12) {
  int wid = threadIdx.x >> 6, lane = threadIdx.x & 63;
  int t = blockIdx.x * 4 + wid;
  const float* xr = x + (size_t)t * D_MODEL;
  float a0 = 0.f, a1 = 0.f, a2 = 0.f, a3 = 0.f;
#pragma unroll
  for (int c = 0; c < 4; ++c) {
    int d0 = c * 256 + lane * 4;
    fvec4 xv = *(const fvec4*)(xr + d0);
#pragma unroll
    for (int j = 0; j < 4; ++j) {
      fvec4 wv = *(const fvec4*)(Wr + (size_t)(d0 + j) * 4);
      a0 += xv[j] * wv[0]; a1 += xv[j] * wv[1];
      a2 += xv[j] * wv[2]; a3 += xv[j] * wv[3];
    }
  }
#pragma unroll
  for (int m = 32; m; m >>= 1) {
    a0 += __shfl_xor(a0, m, 64); a1 += __shfl_xor(a1, m, 64);
    a2 += __shfl_xor(a2, m, 64); a3 += __shfl_xor(a3, m, 64);
  }
  if (lane == 0) {
    float l[4] = {a0 + br[0], a1 + br[1], a2 + br[2], a3 + br[3]};
    int e1 = 0; float m1 = l[0];
#pragma unroll
    for (int e = 1; e < 4; ++e) if (l[e] > m1) { m1 = l[e]; e1 = e; }
    int e2 = -1; float m2 = -1e30f;
#pragma unroll
    for (int e = 0; e < 4; ++e) if (e != e1 && l[e] > m2) { m2 = l[e]; e2 = e; }
    // renormalized top-2 softmax == softmax over the two logits
    float tt = expf(m2 - m1);
    float w1 = 1.f / (1.f + tt), w2 = tt / (1.f + tt);
    atomicAdd(&counts[e1], 1); atomicAdd(&counts[e2], 1);
    e12[t] = e1 | (e2 << 8);
    w12[2 * t] = w1; w12[2 * t + 1] = w2;
  }
}

// ---------------- prefix: 128-aligned expert offsets ----------------
__global__ void prefix_k(const int* __restrict__ counts, int* __restrict__ offs,
                         int* __restrict__ cursor) {
  if (threadIdx.x == 0 && blockIdx.x == 0) {
    int o = 0;
#pragma unroll
    for (int e = 0; e < 4; ++e) {
      offs[e] = o; cursor[e] = o;
      o += (counts[e] + 127) & ~127;
    }
    offs[4] = o;
  }
}

// ---------------- scatter tokens into per-expert lists ----------------
__global__ __launch_bounds__(256) void lists_k(
    const int* __restrict__ e12, const float* __restrict__ w12,
    int* __restrict__ cursor, int* __restrict__ tok, float* __restrict__ wgt) {
  int t = blockIdx.x * 256 + threadIdx.x;
  int p = e12[t];
  int e1 = p & 255, e2 = p >> 8;
  int i1 = atomicAdd(&cursor[e1], 1); tok[i1] = t; wgt[i1] = w12[2 * t];
  int i2 = atomicAdd(&cursor[e2], 1); tok[i2] = t; wgt[i2] = w12[2 * t + 1];
}

// ---------------- gather x rows -> fp16, zero pad rows ----------------
__global__ __launch_bounds__(128) void gather_k(
    const float* __restrict__ x, const int* __restrict__ offs,
    const int* __restrict__ counts, const int* __restrict__ tok,
    _Float16* __restrict__ Xg) {
  int b = blockIdx.x;
  if (b >= offs[4]) return;
  int e = 0;
  while (e < 3 && b >= offs[e + 1]) ++e;
  int tid = threadIdx.x;
  f16x8 o;
  if (b < offs[e] + counts[e]) {
    int t = tok[b];
    const float* src = x + (size_t)t * D_MODEL + tid * 8;
    fvec4 v0 = *(const fvec4*)src;
    fvec4 v1 = *(const fvec4*)(src + 4);
#pragma unroll
    for (int j = 0; j < 4; ++j) { o[j] = (_Float16)v0[j]; o[4 + j] = (_Float16)v1[j]; }
  } else {
#pragma unroll
    for (int j = 0; j < 8; ++j) o[j] = (_Float16)0.f;
  }
  *(f16x8*)(Xg + (size_t)b * D_MODEL + tid * 8) = o;
}

// ---------------- transpose-convert weights: in[e][K][N] fp32 -> out[e][N][K] fp16 ----------------
__global__ __launch_bounds__(256) void wtrans_k(
    const float* __restrict__ in, _Float16* __restrict__ out, int K, int N) {
  __shared__ float tile[64][65];
  int e = blockIdx.z;
  int n0 = blockIdx.x * 64, k0 = blockIdx.y * 64;
  const float* src = in + (size_t)e * K * N;
  _Float16* dst = out + (size_t)e * K * N;
  int t = threadIdx.x;
  {
    int kk = t >> 2, nc = (t & 3) * 16;
    const float* p = src + (size_t)(k0 + kk) * N + n0 + nc;
#pragma unroll
    for (int j = 0; j < 4; ++j) {
      fvec4 v = *(const fvec4*)(p + j * 4);
      tile[kk][nc + j * 4 + 0] = v[0]; tile[kk][nc + j * 4 + 1] = v[1];
      tile[kk][nc + j * 4 + 2] = v[2]; tile[kk][nc + j * 4 + 3] = v[3];
    }
  }
  __syncthreads();
  {
    int nn = t >> 2, kb = (t & 3) * 16;
    f16x8 o0, o1;
#pragma unroll
    for (int j = 0; j < 8; ++j) o0[j] = (_Float16)tile[kb + j][nn];
#pragma unroll
    for (int j = 0; j < 8; ++j) o1[j] = (_Float16)tile[kb + 8 + j][nn];
    _Float16* q = dst + (size_t)(n0 + nn) * K + k0 + kb;
    *(f16x8*)q = o0;
    *((f16x8*)q + 1) = o1;
  }
}

// ---------------- MFMA GEMM: C[128x128] tile, BK=64, 4 waves ----------------
// A: [CAP_ROWS][KDIM] fp16 row-major (global row space, expert regions 128-aligned)
// B: [4][NTOT][KDIM] fp16 (B^T layout)
// MODE 0: outH = f16( gelu(acc + bias) ), stride NTOT
// MODE 1: atomicAdd(outF[tok*1024 + col], wgt * (acc + bias))
template <int KDIM, int MODE>
__global__ __launch_bounds__(256) void gemm_k(
    const _Float16* __restrict__ A, const _Float16* __restrict__ B,
    const float* __restrict__ bias, const int* __restrict__ offs,
    const int* __restrict__ counts, const int* __restrict__ tok,
    const float* __restrict__ wgt, _Float16* __restrict__ outH,
    float* __restrict__ outF, int NTOT) {
  __shared__ uint4 smem[2048];  // 32 KB: A tile 16KB, B tile 16KB
  int rowBase = blockIdx.x * 128;
  if (rowBase >= offs[4]) return;
  int e = 0;
  while (e < 3 && rowBase >= offs[e + 1]) ++e;
  int cnt = counts[e];
  int eoff = offs[e];
  if (rowBase >= eoff + cnt) return;  // pure-pad tile
  int colBase = blockIdx.y * 128;
  int tid = threadIdx.x, wid = tid >> 6, lane = tid & 63;
  int wr = wid >> 1, wc = wid & 1;

  char* ldsA = (char*)smem;
  char* ldsB = (char*)smem + 16384;

  // staging: per issue a wave writes 1KB linear LDS (8 rows x 128B).
  // LDS holds XOR-swizzled layout: byte(row,k) = row*128 + (k*2 ^ ((row&7)<<4)).
  // Achieved by permuting the GLOBAL source 16B-chunk index: kx = (lane&7) ^ (lane>>3).
  int srow = lane >> 3;            // row within 8-row chunk
  int kx = (lane & 7) ^ srow;      // swizzled 16B chunk of the 128B row-slice
  const _Float16* Abase = A + (size_t)rowBase * KDIM + kx * 8;
  const _Float16* Bbase = B + (size_t)e * NTOT * KDIM + (size_t)colBase * KDIM + kx * 8;

  f32x4 acc[4][4];
  f32x4 zero = {0.f, 0.f, 0.f, 0.f};
#pragma unroll
  for (int m = 0; m < 4; ++m)
#pragma unroll
    for (int n = 0; n < 4; ++n) acc[m][n] = zero;

  for (int k0 = 0; k0 < KDIM; k0 += 64) {
#pragma unroll
    for (int i = 0; i < 4; ++i) {
      int chunk = wid * 4 + i;       // 0..15
      int row = chunk * 8 + srow;    // 0..127
      gload_lds16(Abase + (size_t)row * KDIM + k0, ldsA + chunk * 1024);
      gload_lds16(Bbase + (size_t)row * KDIM + k0, ldsB + chunk * 1024);
    }
    __syncthreads();
#pragma unroll
    for (int kk = 0; kk < 2; ++kk) {
      f16x8 af[4], bfr[4];
      int kbyte = kk * 64 + (lane >> 4) * 16;
#pragma unroll
      for (int m = 0; m < 4; ++m) {
        int row = wr * 64 + m * 16 + (lane & 15);
        int byt = row * 128 + (kbyte ^ ((row & 7) << 4));
        af[m] = *(const f16x8*)(ldsA + byt);
      }
#pragma unroll
      for (int n = 0; n < 4; ++n) {
        int row = wc * 64 + n * 16 + (lane & 15);
        int byt = row * 128 + (kbyte ^ ((row & 7) << 4));
        bfr[n] = *(const f16x8*)(ldsB + byt);
      }
#pragma unroll
      for (int m = 0; m < 4; ++m)
#pragma unroll
        for (int n = 0; n < 4; ++n)
          acc[m][n] = __builtin_amdgcn_mfma_f32_16x16x32_f16(af[m], bfr[n], acc[m][n], 0, 0, 0);
    }
    __syncthreads();
  }

  // epilogue: C/D frag mapping: col = lane&15, row = (lane>>4)*4 + j
  int col0 = colBase + wc * 64 + (lane & 15);
  float bv[4];
#pragma unroll
  for (int n = 0; n < 4; ++n) bv[n] = bias[(size_t)e * NTOT + col0 + n * 16];

  if (MODE == 0) {
#pragma unroll
    for (int m = 0; m < 4; ++m) {
      int growBase = rowBase + wr * 64 + m * 16 + (lane >> 4) * 4;
#pragma unroll
      for (int j = 0; j < 4; ++j) {
        size_t rowoff = (size_t)(growBase + j) * NTOT;
#pragma unroll
        for (int n = 0; n < 4; ++n) {
          float v = acc[m][n][j] + bv[n];
          v = 0.5f * v * (1.f + erff(v * 0.70710678118654752f));
          outH[rowoff + col0 + n * 16] = (_Float16)v;
        }
      }
    }
  } else {
#pragma unroll
    for (int m = 0; m < 4; ++m) {
      int growBase = rowBase + wr * 64 + m * 16 + (lane >> 4) * 4;
#pragma unroll
      for (int j = 0; j < 4; ++j) {
        int grow = growBase + j;
        if (grow - eoff < cnt) {
          int t = tok[grow];
          float w = wgt[grow];
          size_t o = (size_t)t * D_MODEL + col0;
#pragma unroll
          for (int n = 0; n < 4; ++n)
            atomicAdd(&outF[o + n * 16], w * (acc[m][n][j] + bv[n]));
        }
      }
    }
  }
}

extern "C" void kernel_launch(void* const* d_in, const int* in_sizes, int n_in,
                              void* d_out, int out_size, void* d_ws, size_t ws_size,
                              hipStream_t stream) {
  const float* x  = (const float*)d_in[0];
  const float* Wr = (const float*)d_in[1];
  const float* br = (const float*)d_in[2];
  const float* W1 = (const float*)d_in[3];
  const float* b1 = (const float*)d_in[4];
  const float* W2 = (const float*)d_in[5];
  const float* b2 = (const float*)d_in[6];
  float* out = (float*)d_out;
  char* ws = (char*)d_ws;
  if (ws_size < WS_NEED) return;

  _Float16* W1f = (_Float16*)(ws + OFF_W1);
  _Float16* W2f = (_Float16*)(ws + OFF_W2);
  _Float16* Xg  = (_Float16*)(ws + OFF_XG);
  _Float16* H   = (_Float16*)(ws + OFF_H);
  int*   counts = (int*)(ws + OFF_CNT);
  int*   cursor = (int*)(ws + OFF_CUR);
  int*   offs   = (int*)(ws + OFF_OFS);
  int*   tok    = (int*)(ws + OFF_TOK);
  float* wgt    = (float*)(ws + OFF_WGT);
  int*   e12    = (int*)(ws + OFF_E12);
  float* w12    = (float*)(ws + OFF_W12);

  hipMemsetAsync(counts, 0, 16, stream);
  hipMemsetAsync(d_out, 0, (size_t)out_size * sizeof(float), stream);

  router_k<<<NTOK / 4, 256, 0, stream>>>(x, Wr, br, counts, e12, w12);
  prefix_k<<<1, 64, 0, stream>>>(counts, offs, cursor);
  lists_k<<<NTOK / 256, 256, 0, stream>>>(e12, w12, cursor, tok, wgt);
  gather_k<<<CAP_ROWS, 128, 0, stream>>>(x, offs, counts, tok, Xg);
  wtrans_k<<<dim3(64, 16, 4), 256, 0, stream>>>(W1, W1f, 1024, 4096);
  wtrans_k<<<dim3(16, 64, 4), 256, 0, stream>>>(W2, W2f, 4096, 1024);

  // GEMM1: h = gelu(Xg @ W1 + b1), M=rows, N=4096, K=1024
  gemm_k<1024, 0><<<dim3(CAP_ROWS / 128, D_FF / 128), 256, 0, stream>>>(
      Xg, W1f, b1, offs, counts, tok, wgt, H, nullptr, D_FF);
  // GEMM2: out[tok] += w * (h @ W2 + b2), N=1024, K=4096
  gemm_k<4096, 1><<<dim3(CAP_ROWS / 128, D_MODEL / 128), 256, 0, stream>>>(
      H, W2f, b2, offs, counts, tok, wgt, nullptr, out, D_MODEL);
}